// Round 1
// baseline (172.145 us; speedup 1.0000x reference)
//
#include <hip/hip_runtime.h>

// Problem constants (from reference)
#define EMB        128
#define NTOT       128   // 32 + 32 + 64
#define OFF_SGAP   32
#define OFF_PCOUNT 64

// out[b,s] = [ vt[b,s,:] * (W[:,r] + W[:,32+s'] + W[:,64+p']) , one_hot_concat ]
// One wave (64 lanes) per row: lanes 0-31 -> theta (float4 each),
// lanes 32-63 -> ct one-hot (float4 each). Whole wave writes contiguous 1 KiB.
__global__ __launch_bounds__(512) void fused_onehot_linear(
    const float* __restrict__ vt,
    const int*   __restrict__ rgap,
    const int*   __restrict__ sgap,
    const int*   __restrict__ pcount,
    const float* __restrict__ W,     // [EMB][NTOT] row-major
    float*       __restrict__ out,   // [rows][EMB + NTOT]
    int nrows)
{
    // LDS: W transposed -> wt[idx][e] contiguous in e (64 KiB)
    __shared__ float wt[NTOT * EMB];

    // Stage transpose. Write index w = i*EMB + e with consecutive threads ->
    // consecutive e -> conflict-free ds_write. Read W[e*NTOT + i] is strided
    // but W is 64 KiB and L2-resident; staging is once per block.
    for (int w = threadIdx.x; w < NTOT * EMB; w += blockDim.x) {
        int i = w >> 7;        // w / EMB
        int e = w & (EMB - 1); // w % EMB
        wt[w] = W[e * NTOT + i];
    }
    __syncthreads();

    const int wave = threadIdx.x >> 6;
    const int lane = threadIdx.x & 63;
    const int wpb  = blockDim.x >> 6;       // waves per block
    const int stride = gridDim.x * wpb;     // rows per grid step

    const float4* vt4  = (const float4*)vt;
    float4*       out4 = (float4*)out;

    for (int row = blockIdx.x * wpb + wave; row < nrows; row += stride) {
        // wave-uniform index loads (broadcast)
        const int r0 = rgap[row];
        const int s0 = OFF_SGAP + sgap[row];
        const int p0 = OFF_PCOUNT + pcount[row];
        const int orow = row * 64;          // row * 256 floats / 4

        if (lane < 32) {
            // theta half: e = lane*4 .. lane*4+3
            float4 v = vt4[row * 32 + lane];
            const float4* cr = (const float4*)&wt[r0 * EMB];
            const float4* cs = (const float4*)&wt[s0 * EMB];
            const float4* cp = (const float4*)&wt[p0 * EMB];
            float4 a = cr[lane];
            float4 b = cs[lane];
            float4 c = cp[lane];
            float4 t;
            t.x = v.x * (a.x + b.x + c.x);
            t.y = v.y * (a.y + b.y + c.y);
            t.z = v.z * (a.z + b.z + c.z);
            t.w = v.w * (a.w + b.w + c.w);
            out4[orow + lane] = t;
        } else {
            // ct half: positions p .. p+3 within the 128-wide one-hot concat.
            // r0 < 32 <= s0 < 64 <= p0 < 128 are disjoint, so a flat compare works.
            const int p = (lane - 32) * 4;
            float4 t;
            t.x = (p     == r0 || p     == s0 || p     == p0) ? 1.0f : 0.0f;
            t.y = (p + 1 == r0 || p + 1 == s0 || p + 1 == p0) ? 1.0f : 0.0f;
            t.z = (p + 2 == r0 || p + 2 == s0 || p + 2 == p0) ? 1.0f : 0.0f;
            t.w = (p + 3 == r0 || p + 3 == s0 || p + 3 == p0) ? 1.0f : 0.0f;
            out4[orow + lane] = t;   // 32 + (lane-32) == lane
        }
    }
}

extern "C" void kernel_launch(void* const* d_in, const int* in_sizes, int n_in,
                              void* d_out, int out_size, void* d_ws, size_t ws_size,
                              hipStream_t stream) {
    const float* vt     = (const float*)d_in[0];
    const int*   rgap   = (const int*)d_in[1];
    const int*   sgap   = (const int*)d_in[2];
    const int*   pcount = (const int*)d_in[3];
    const float* W      = (const float*)d_in[4];
    float*       out    = (float*)d_out;

    const int nrows = in_sizes[1];          // B*S = 262144
    const int block = 512;                  // 8 waves
    const int wpb   = block / 64;
    int grid = (nrows + wpb - 1) / wpb;     // one wave per row
    if (grid > 2048) grid = 2048;           // grid-stride; amortize LDS staging

    fused_onehot_linear<<<grid, block, 0, stream>>>(vt, rgap, sgap, pcount, W,
                                                    out, nrows);
}

// Round 2
// 92.875 us; speedup vs baseline: 1.8535x; 1.8535x over previous
//
#include <hip/hip_runtime.h>

#define EMB        128
#define NTOT       128   // 32 + 32 + 64
#define OFF_SGAP   32
#define OFF_PCOUNT 64

// Kernel 1: transpose W [EMB][NTOT] -> Wt [NTOT][EMB] in workspace (64 KiB).
__global__ __launch_bounds__(256) void transpose_W(
    const float* __restrict__ W, float* __restrict__ Wt)
{
    int t = blockIdx.x * blockDim.x + threadIdx.x;   // 0 .. NTOT*EMB-1
    int i = t >> 7;          // column index in W  (0..127)
    int e = t & (EMB - 1);   // row index in W     (0..127)
    Wt[t] = W[e * NTOT + i]; // write coalesced, read strided (64 KiB, L2)
}

// Kernel 2: one half-wave (32 lanes) per row; lane owns one float4 of theta
// and one float4 of ct. No LDS, no loop, no divergent branch -> full-width
// 1 KiB vt loads per wave, max occupancy.
__global__ __launch_bounds__(256, 8) void fused_rows(
    const float* __restrict__ vt,
    const int*   __restrict__ rgap,
    const int*   __restrict__ sgap,
    const int*   __restrict__ pcount,
    const float* __restrict__ Wt,    // [NTOT][EMB]
    float*       __restrict__ out,   // [rows][EMB + NTOT]
    int nrows)
{
    const int gtid = blockIdx.x * blockDim.x + threadIdx.x;
    const int row  = gtid >> 5;          // 32 lanes per row
    const int l    = gtid & 31;          // float4 slot within the row half
    if (row >= nrows) return;

    // per-half-wave uniform indices (broadcast loads)
    const int r0 = rgap[row];
    const int s0 = OFF_SGAP   + sgap[row];
    const int p0 = OFF_PCOUNT + pcount[row];

    const float4* vt4  = (const float4*)vt;
    const float4* wt4  = (const float4*)Wt;
    float4*       out4 = (float4*)out;

    // theta: vt[row, l*4..l*4+3] * (Wt[r0] + Wt[s0] + Wt[p0]) same slice
    float4 v = vt4[row * 32 + l];        // contiguous 1 KiB across the wave
    float4 a = wt4[r0 * 32 + l];         // 512 B contiguous, L1/L2 hit
    float4 b = wt4[s0 * 32 + l];
    float4 c = wt4[p0 * 32 + l];
    float4 t;
    t.x = v.x * (a.x + b.x + c.x);
    t.y = v.y * (a.y + b.y + c.y);
    t.z = v.z * (a.z + b.z + c.z);
    t.w = v.w * (a.w + b.w + c.w);
    out4[row * 64 + l] = t;

    // ct: one-hot concat, positions p..p+3 of 128. r0<32<=s0<64<=p0<128 are
    // disjoint so flat compares suffice.
    const int p = l * 4;
    float4 u;
    u.x = (p     == r0 || p     == s0 || p     == p0) ? 1.0f : 0.0f;
    u.y = (p + 1 == r0 || p + 1 == s0 || p + 1 == p0) ? 1.0f : 0.0f;
    u.z = (p + 2 == r0 || p + 2 == s0 || p + 2 == p0) ? 1.0f : 0.0f;
    u.w = (p + 3 == r0 || p + 3 == s0 || p + 3 == p0) ? 1.0f : 0.0f;
    out4[row * 64 + 32 + l] = u;
}

extern "C" void kernel_launch(void* const* d_in, const int* in_sizes, int n_in,
                              void* d_out, int out_size, void* d_ws, size_t ws_size,
                              hipStream_t stream) {
    const float* vt     = (const float*)d_in[0];
    const int*   rgap   = (const int*)d_in[1];
    const int*   sgap   = (const int*)d_in[2];
    const int*   pcount = (const int*)d_in[3];
    const float* W      = (const float*)d_in[4];
    float*       out    = (float*)d_out;
    float*       Wt     = (float*)d_ws;      // 64 KiB scratch

    const int nrows = in_sizes[1];           // B*S = 262144

    transpose_W<<<(NTOT * EMB) / 256, 256, 0, stream>>>(W, Wt);

    // 32 lanes per row -> nrows*32 threads total
    const long long threads = (long long)nrows * 32;
    const int block = 256;
    const int grid  = (int)((threads + block - 1) / block);
    fused_rows<<<grid, block, 0, stream>>>(vt, rgap, sgap, pcount, Wt, out, nrows);
}

// Round 4
// 63.983 us; speedup vs baseline: 2.6905x; 1.4516x over previous
//
#include <hip/hip_runtime.h>

#define EMB        128
#define NTOT       128   // 32 + 32 + 64
#define OFF_SGAP   32
#define OFF_PCOUNT 64
#define ROWS       4     // rows per half-wave

typedef float f4 __attribute__((ext_vector_type(4)));  // native vec -> NT builtin OK

// Kernel 1: transpose W [EMB][NTOT] -> Wt [NTOT][EMB] in workspace (64 KiB).
__global__ __launch_bounds__(256) void transpose_W(
    const float* __restrict__ W, float* __restrict__ Wt)
{
    int t = blockIdx.x * blockDim.x + threadIdx.x;   // 0 .. NTOT*EMB-1
    int i = t >> 7;          // column index in W  (0..127)
    int e = t & (EMB - 1);   // row index in W     (0..127)
    Wt[t] = W[e * NTOT + i]; // write coalesced, read strided (64 KiB, L2)
}

// Kernel 2: one half-wave (32 lanes) per ROWS consecutive rows.
// Batch all independent loads (indices + vt) for ROWS rows first, then the
// dependent Wt gathers + compute + stores. ~16 outstanding VMEM ops/thread
// hides the index-load -> gather chain latency.
__global__ __launch_bounds__(256, 4) void fused_rows(
    const float* __restrict__ vt,
    const int*   __restrict__ rgap,
    const int*   __restrict__ sgap,
    const int*   __restrict__ pcount,
    const float* __restrict__ Wt,    // [NTOT][EMB]
    float*       __restrict__ out,   // [rows][EMB + NTOT]
    int nrows)
{
    const int gtid = blockIdx.x * blockDim.x + threadIdx.x;
    const int hw   = gtid >> 5;          // half-wave id
    const int l    = gtid & 31;          // f4 slot within row half
    const int row0 = hw * ROWS;
    if (row0 >= nrows) return;

    const f4* vt4  = (const f4*)vt;
    const f4* wt4  = (const f4*)Wt;
    f4*       out4 = (f4*)out;

    // Phase 1: independent loads for all ROWS rows (indices + vt slices).
    int r[ROWS], s[ROWS], p[ROWS];
    f4  v[ROWS];
#pragma unroll
    for (int k = 0; k < ROWS; ++k) {
        const int row = row0 + k;
        r[k] = rgap[row];
        s[k] = OFF_SGAP   + sgap[row];
        p[k] = OFF_PCOUNT + pcount[row];
        v[k] = vt4[row * 32 + l];
    }

    // Phase 2: dependent gathers + compute + stores.
#pragma unroll
    for (int k = 0; k < ROWS; ++k) {
        const int row = row0 + k;
        f4 a = wt4[r[k] * 32 + l];   // 512 B contiguous, L1/L2 hit
        f4 b = wt4[s[k] * 32 + l];
        f4 c = wt4[p[k] * 32 + l];
        f4 t = v[k] * (a + b + c);
        __builtin_nontemporal_store(t, &out4[row * 64 + l]);

        // ct: one-hot concat positions q..q+3 of 128; r<32<=s<64<=p<128 are
        // disjoint so flat compares suffice.
        const int q = l * 4;
        f4 u;
        u.x = (q     == r[k] || q     == s[k] || q     == p[k]) ? 1.0f : 0.0f;
        u.y = (q + 1 == r[k] || q + 1 == s[k] || q + 1 == p[k]) ? 1.0f : 0.0f;
        u.z = (q + 2 == r[k] || q + 2 == s[k] || q + 2 == p[k]) ? 1.0f : 0.0f;
        u.w = (q + 3 == r[k] || q + 3 == s[k] || q + 3 == p[k]) ? 1.0f : 0.0f;
        __builtin_nontemporal_store(u, &out4[row * 64 + 32 + l]);
    }
}

extern "C" void kernel_launch(void* const* d_in, const int* in_sizes, int n_in,
                              void* d_out, int out_size, void* d_ws, size_t ws_size,
                              hipStream_t stream) {
    const float* vt     = (const float*)d_in[0];
    const int*   rgap   = (const int*)d_in[1];
    const int*   sgap   = (const int*)d_in[2];
    const int*   pcount = (const int*)d_in[3];
    const float* W      = (const float*)d_in[4];
    float*       out    = (float*)d_out;
    float*       Wt     = (float*)d_ws;      // 64 KiB scratch

    const int nrows = in_sizes[1];           // B*S = 262144

    transpose_W<<<(NTOT * EMB) / 256, 256, 0, stream>>>(W, Wt);

    // one half-wave (32 threads) per ROWS rows
    const long long threads = ((long long)nrows / ROWS) * 32;
    const int block = 256;
    const int grid  = (int)((threads + block - 1) / block);
    fused_rows<<<grid, block, 0, stream>>>(vt, rgap, sgap, pcount, Wt, out, nrows);
}